// Round 4
// baseline (577.339 us; speedup 1.0000x reference)
//
#include <hip/hip_runtime.h>

#define NN 50000
#define NE 800000
#define D 64

typedef float f32x4 __attribute__((ext_vector_type(4)));
typedef unsigned short u16x4 __attribute__((ext_vector_type(4)));

__device__ __forceinline__ float b2f(unsigned short h) {
    unsigned int u = ((unsigned int)h) << 16;
    return __builtin_bit_cast(float, u);
}
__device__ __forceinline__ unsigned short f2bf(float f) {
    unsigned int u = __builtin_bit_cast(unsigned int, f);
    u = (u + 0x7fffu + ((u >> 16) & 1u)) >> 16;
    return (unsigned short)u;
}

// ---------------------------------------------------------------------------
// pre (VALU, no MFMA, no layout assumptions):
//   u = bf16( x @ (W_top - W_bot) + b_edge ),  v = bf16( x @ W_bot )
// One node per wave; W staged in LDS [k][c]; lane owns one output column.
// ---------------------------------------------------------------------------
__global__ __launch_bounds__(256) void pre_valu(
    const float* __restrict__ x,
    const float* __restrict__ W_edge,
    const float* __restrict__ b_edge,
    unsigned short* __restrict__ u,
    unsigned short* __restrict__ v)
{
    __shared__ float Wu[D * D];   // (W_top - W_bot)[k][c]
    __shared__ float Wv[D * D];   // W_bot[k][c]
    for (int i = threadIdx.x; i < D * D; i += 256) {
        float wt = W_edge[i];            // rows 0..63   (x_i weight)
        float wb = W_edge[D * D + i];    // rows 64..127 (x_j - x_i weight)
        Wu[i] = wt - wb;
        Wv[i] = wb;
    }
    __syncthreads();

    const int col   = threadIdx.x & 63;
    const int local = threadIdx.x >> 6;   // wave id in block (0..3)
    const float bias = b_edge[col];

    for (int node = blockIdx.x * 4 + local; node < NN; node += gridDim.x * 4) {
        const float* xr = x + (size_t)node * D;
        float su = bias, sv = 0.f;
#pragma unroll 8
        for (int k = 0; k < D; ++k) {
            float xv = xr[k];                    // wave-uniform -> broadcast
            su += xv * Wu[k * D + col];          // 2-way bank alias (free)
            sv += xv * Wv[k * D + col];
        }
        u[(size_t)node * D + col] = f2bf(su);
        v[(size_t)node * D + col] = f2bf(sv);
    }
}

// ---------------------------------------------------------------------------
// edge: agg[dst] = max(agg[dst], relu(u[dst] + v[src])) via int atomicMax.
// Plain and boring: no speculative filter. m<=0 can never beat 0-init, so
// skipping it is exact. int compare == float compare for non-negative floats.
// ---------------------------------------------------------------------------
__global__ __launch_bounds__(256) void edge_kernel(
    const int* __restrict__ ei,
    const unsigned short* __restrict__ u,
    const unsigned short* __restrict__ v,
    int* __restrict__ agg)
{
    const int lane = threadIdx.x & 63;
    const int wave = threadIdx.x >> 6;
    const int sub = lane >> 4;      // edge within quad (0..3)
    const int q   = lane & 15;      // col group (cols q*4 .. q*4+3)

    const bool is64 = ((ei[1] | ei[3] | ei[5] | ei[7]) == 0);
    const long long* __restrict__ ei64 = (const long long*)ei;

    const int gw = blockIdx.x * 4 + wave;
    const int nw = gridDim.x * 4;
    const int niter = NE / 4;       // 200000
    for (int it = gw; it < niter; it += nw) {
        int e = it * 4 + sub;
        int se, de;
        if (is64) {
            se = (int)ei64[e];
            de = (int)ei64[NE + e];
        } else {
            se = ei[e];
            de = ei[NE + e];
        }
        u16x4 uu = *(const u16x4*)(u + (size_t)de * D + q * 4);
        u16x4 vv = *(const u16x4*)(v + (size_t)se * D + q * 4);
        int* aggrow = agg + (size_t)de * D + q * 4;
#pragma unroll
        for (int c = 0; c < 4; ++c) {
            float m = b2f(uu[c]) + b2f(vv[c]);
            if (m > 0.f) atomicMax(aggrow + c, __builtin_bit_cast(int, m));
        }
    }
}

// ---------------------------------------------------------------------------
// final (VALU, no MFMA): out = agg + x @ W_res + b_res   (all fp32)
// ---------------------------------------------------------------------------
__global__ __launch_bounds__(256) void final_valu(
    const float* __restrict__ x,
    const float* __restrict__ W_res,
    const float* __restrict__ b_res,
    const float* __restrict__ agg,
    float* __restrict__ out)
{
    __shared__ float Wr[D * D];   // W_res[k][c]
    for (int i = threadIdx.x; i < D * D; i += 256) Wr[i] = W_res[i];
    __syncthreads();

    const int col   = threadIdx.x & 63;
    const int local = threadIdx.x >> 6;
    const float bias = b_res[col];

    for (int node = blockIdx.x * 4 + local; node < NN; node += gridDim.x * 4) {
        const float* xr = x + (size_t)node * D;
        float s = bias;
#pragma unroll 8
        for (int k = 0; k < D; ++k)
            s += xr[k] * Wr[k * D + col];
        out[(size_t)node * D + col] = s + agg[(size_t)node * D + col];
    }
}

extern "C" void kernel_launch(void* const* d_in, const int* in_sizes, int n_in,
                              void* d_out, int out_size, void* d_ws, size_t ws_size,
                              hipStream_t stream) {
    const float* x      = (const float*)d_in[0];
    const int*   ei     = (const int*)d_in[1];
    const float* W_edge = (const float*)d_in[2];
    const float* b_edge = (const float*)d_in[3];
    const float* W_res  = (const float*)d_in[4];
    const float* b_res  = (const float*)d_in[5];
    float* out = (float*)d_out;

    // workspace layout: agg f32 [NN*D] | u bf16 [NN*D] | v bf16 [NN*D]  = 25.6 MB
    float* agg = (float*)d_ws;
    unsigned short* u = (unsigned short*)((char*)d_ws + (size_t)NN * D * 4);
    unsigned short* v = u + (size_t)NN * D;

    hipMemsetAsync(d_ws, 0, (size_t)NN * D * sizeof(float), stream);   // agg = 0
    pre_valu<<<1024, 256, 0, stream>>>(x, W_edge, b_edge, u, v);
    edge_kernel<<<2048, 256, 0, stream>>>(ei, u, v, (int*)agg);
    final_valu<<<1024, 256, 0, stream>>>(x, W_res, b_res, agg, out);
}